// Round 6
// baseline (83.774 us; speedup 1.0000x reference)
//
#include <hip/hip_runtime.h>

// ModalitySpecificLocalSelfAttention — MI355X. f32 I/O, bf16 MFMA internals.
// cvt (weights + zero k/v pads) -> qkv (conv1+conv2+v, 16-wave/CU) ->
// fused attention(16 lanes/px, padded unconditional taps) + final conv.

typedef short short8 __attribute__((ext_vector_type(8)));
typedef float f32x4 __attribute__((ext_vector_type(4)));

#define HW_PIX 16384   // H*W
#define CH 128
#define PADW 134       // 128 + 2*3
#define PROW (PADW * CH)   // padded row stride in elems (17152)

// ws layout in 16-bit units
#define WQ1_OFF 0
#define WQ2_OFF 16384
#define WK1_OFF 32768
#define WK2_OFF 49152
#define WV_OFF  65536
#define WO_OFF  81920            // 128x256
#define SB_OFF  114688           // 1536 f32 (3072 shorts)
#define TQ_OFF  131072           // q [p][c], 2,097,152
#define KP_OFF  (TQ_OFF + 2097152)        // k padded [134*134][128] = 2,297,408
#define VP_OFF  (KP_OFF + 2297408)        // v padded
#define XT_OFF  (VP_OFF + 2297408)        // x bf16 [p][c]

static __device__ __forceinline__ float bf2f(unsigned short u) {
    union { unsigned int i; float f; } c; c.i = ((unsigned int)u) << 16; return c.f;
}
static __device__ __forceinline__ unsigned short f2bf(float f) {
    union { unsigned int i; float f; } c; c.f = f;
    unsigned int x = c.i;
    return (unsigned short)((x + 0x7fffu + ((x >> 16) & 1u)) >> 16);  // RNE
}

// ---- weights/scale-bias conversion + k/v pad zeroing ----
struct CvtArgs { const float* w[6]; const float* sb[12]; };

__global__ __launch_bounds__(256)
void cvt_k(CvtArgs a, short* __restrict__ ws)
{
    const int u = blockIdx.x * 256 + threadIdx.x;   // 75 blocks = 19200 units
    if (u < 14336) {                                 // 114688 weight elems
        const int s0 = u * 8;
        const int seg = (s0 < 81920) ? (s0 >> 14) : 5;
        const int base = (seg < 5) ? (seg << 14) : 81920;
        const float* fp = a.w[seg] + (s0 - base);
        short8 o;
        #pragma unroll
        for (int j = 0; j < 8; ++j) o[j] = (short)f2bf(fp[j]);
        *(short8*)(ws + s0) = o;
    } else if (u < 15872) {                          // 1536 scale/bias floats
        const int idx = u - 14336;
        ((float*)(ws + SB_OFF))[idx] = a.sb[idx >> 7][idx & 127];
    } else if (u < 15872 + 3144) {                   // zero pad pixels of k,v
        const int idx = u - 15872;
        const int buf = idx / 1572;                  // 0 = k, 1 = v
        const int e   = idx % 1572;
        int row, col;
        if (e < 402)      { row = e / PADW;          col = e % PADW; }
        else if (e < 804) { row = 131 + (e - 402) / PADW; col = (e - 402) % PADW; }
        else { const int r = e - 804; row = 3 + r / 6; const int c = r % 6;
               col = (c < 3) ? c : (128 + c); }
        short* p = ws + (buf ? VP_OFF : KP_OFF) + (row * PADW + col) * CH;
        const short8 z = {0, 0, 0, 0, 0, 0, 0, 0};
        #pragma unroll
        for (int j = 0; j < 16; ++j) *(short8*)(p + j * 8) = z;
    }
}

// ---- fused q=conv2(conv1(x)), k=conv2(conv1(x)), v=conv(x); emits xT ----
// 1024 blocks x 256 thr; tile = 16 px; wave owns 16 px x 32 och.
__global__ __launch_bounds__(256)
void qkv_k(const float* __restrict__ x, short* __restrict__ ws)
{
    const float* sb = (const float*)(ws + SB_OFF);
    const int tid = threadIdx.x;
    const int l16 = tid & 15;
    const int g   = (tid & 63) >> 4;
    const int wv  = tid >> 6;
    const int o0  = wv * 32;
    const int p0  = blockIdx.x * 16;
    const int p_row = p0 + l16;
    const int h = p0 >> 7, w0 = p0 & 127;

    __shared__ short tileQ[16 * 136];
    __shared__ short tileK[16 * 136];
    __shared__ short tileV[16 * 136];

    // x A-fragments (f32 [c][p] -> bf16), reused for q1/k1/v
    short8 xa[4];
    #pragma unroll
    for (int kk = 0; kk < 4; ++kk) {
        const float* src = x + (kk * 32 + g * 8) * HW_PIX + p_row;
        #pragma unroll
        for (int j = 0; j < 8; ++j) xa[kk][j] = (short)f2bf(src[j * HW_PIX]);
    }
    // xT bf16 [p][c]: wave wv writes its kk==wv chunk (16 px x 32 ch each)
    *(short8*)(ws + XT_OFF + p_row * CH + wv * 32 + g * 8) = xa[wv];

    const f32x4 z = {0.f, 0.f, 0.f, 0.f};
    f32x4 acc[2];

    // ---- stage 1 GEMMs ----
    #define GEMM1(WOFF, SIDX, TILE)                                              \
    {                                                                            \
        acc[0] = z; acc[1] = z;                                                  \
        _Pragma("unroll")                                                        \
        for (int kk = 0; kk < 4; ++kk) {                                         \
            _Pragma("unroll")                                                    \
            for (int nt = 0; nt < 2; ++nt) {                                     \
                short8 bv = *(const short8*)(ws + WOFF +                         \
                    (o0 + nt * 16 + l16) * 128 + kk * 32 + g * 8);               \
                acc[nt] = __builtin_amdgcn_mfma_f32_16x16x32_bf16(xa[kk], bv, acc[nt], 0, 0, 0); \
            }                                                                    \
        }                                                                        \
        _Pragma("unroll")                                                        \
        for (int nt = 0; nt < 2; ++nt) {                                         \
            const int o = o0 + nt * 16 + l16;                                    \
            const float sf = sb[(SIDX) * 128 + o], bf = sb[(SIDX + 1) * 128 + o];\
            _Pragma("unroll")                                                    \
            for (int i = 0; i < 4; ++i) {                                        \
                const float vl = fmaxf(acc[nt][i] * sf + bf, 0.f);               \
                TILE[(g * 4 + i) * 136 + o] = (short)f2bf(vl);                   \
            }                                                                    \
        }                                                                        \
    }
    GEMM1(WQ1_OFF, 0, tileQ)
    GEMM1(WK1_OFF, 4, tileK)
    GEMM1(WV_OFF,  8, tileV)
    #undef GEMM1

    __syncthreads();

    // ---- stage 2: q2/k2 over LDS tiles ----
    short8 lf[4];
    f32x4 accQ[2], accK[2];
    accQ[0] = z; accQ[1] = z; accK[0] = z; accK[1] = z;
    #pragma unroll
    for (int kk = 0; kk < 4; ++kk) lf[kk] = *(const short8*)(tileQ + l16 * 136 + kk * 32 + g * 8);
    #pragma unroll
    for (int kk = 0; kk < 4; ++kk) {
        #pragma unroll
        for (int nt = 0; nt < 2; ++nt) {
            short8 bv = *(const short8*)(ws + WQ2_OFF + (o0 + nt * 16 + l16) * 128 + kk * 32 + g * 8);
            accQ[nt] = __builtin_amdgcn_mfma_f32_16x16x32_bf16(lf[kk], bv, accQ[nt], 0, 0, 0);
        }
    }
    #pragma unroll
    for (int kk = 0; kk < 4; ++kk) lf[kk] = *(const short8*)(tileK + l16 * 136 + kk * 32 + g * 8);
    #pragma unroll
    for (int kk = 0; kk < 4; ++kk) {
        #pragma unroll
        for (int nt = 0; nt < 2; ++nt) {
            short8 bv = *(const short8*)(ws + WK2_OFF + (o0 + nt * 16 + l16) * 128 + kk * 32 + g * 8);
            accK[nt] = __builtin_amdgcn_mfma_f32_16x16x32_bf16(lf[kk], bv, accK[nt], 0, 0, 0);
        }
    }

    __syncthreads();   // all tile reads done before overwrite

    #pragma unroll
    for (int nt = 0; nt < 2; ++nt) {
        const int o = o0 + nt * 16 + l16;
        const float sfq = sb[2 * 128 + o], bfq = sb[3 * 128 + o];
        const float sfk = sb[6 * 128 + o], bfk = sb[7 * 128 + o];
        #pragma unroll
        for (int i = 0; i < 4; ++i) {
            tileQ[(g * 4 + i) * 136 + o] = (short)f2bf(fmaxf(accQ[nt][i] * sfq + bfq, 0.f));
            tileK[(g * 4 + i) * 136 + o] = (short)f2bf(fmaxf(accK[nt][i] * sfk + bfk, 0.f));
        }
    }

    __syncthreads();

    // ---- coalesced stores: q unpadded; k,v into padded layout ----
    {
        const int row = tid >> 4, c8 = tid & 15;       // 256 units of 8 elems
        const int soff = row * 136 + c8 * 8;
        const int prow_pad = (h + 3) * PADW + (w0 + row + 3);
        *(short8*)(ws + TQ_OFF + (p0 + row) * CH + c8 * 8) = *(const short8*)(tileQ + soff);
        *(short8*)(ws + KP_OFF + prow_pad * CH + c8 * 8)   = *(const short8*)(tileK + soff);
        *(short8*)(ws + VP_OFF + prow_pad * CH + c8 * 8)   = *(const short8*)(tileV + soff);
    }
}

// ---- fused 7x7 attention (16 lanes/px, padded k/v) + final conv ----
// 1024 blocks x 256 thr; tile = 16 px; XCD-swizzled.
__global__ __launch_bounds__(256)
void fused_k(const short* __restrict__ ws, float* __restrict__ out)
{
    const short* q  = ws + TQ_OFF;
    const short* kp = ws + KP_OFF;
    const short* vp = ws + VP_OFF;
    const short* xT = ws + XT_OFF;
    const short* Wo = ws + WO_OFF;
    const float* sb = (const float*)(ws + SB_OFF);

    __shared__ short lds[3072];   // phase1: att [16][136]; phase2: out [128][24]

    const int tid = threadIdx.x;
    const int b   = blockIdx.x;
    const int t   = (b & 7) * 128 + (b >> 3);       // XCD-contiguous tiles
    const int p0  = t * 16;
    const int h = p0 >> 7, w0 = p0 & 127;

    // ---- phase 1: attention ----
    {
        const int lane16 = tid & 15;          // channel group
        const int prw = tid >> 4;             // pixel 0..15
        const int p = p0 + prw;
        const int cb = lane16 * 8;
        const int base0 = ((h + 3) * PADW + (w0 + prw + 3)) * CH + cb;

        float qf[8];
        {
            short8 qv = *(const short8*)(q + p * CH + cb);
            #pragma unroll
            for (int j = 0; j < 8; ++j) qf[j] = bf2f((unsigned short)qv[j]);
        }

        float e[49];
        #pragma unroll
        for (int off = 0; off < 49; ++off) {
            const int di = off / 7 - 3, dj = off % 7 - 3;
            short8 kv = *(const short8*)(kp + base0 + (di * PADW + dj) * CH);
            float s = 0.f;
            #pragma unroll
            for (int j = 0; j < 8; ++j) s += qf[j] * bf2f((unsigned short)kv[j]);
            s += __shfl_xor(s, 1, 16);
            s += __shfl_xor(s, 2, 16);
            s += __shfl_xor(s, 4, 16);
            s += __shfl_xor(s, 8, 16);
            e[off] = s;
        }

        float m = e[0];
        #pragma unroll
        for (int off = 1; off < 49; ++off) m = fmaxf(m, e[off]);
        float Z = 0.f;
        #pragma unroll
        for (int off = 0; off < 49; ++off) { const float ex = __expf(e[off] - m); e[off] = ex; Z += ex; }
        const float rz = 1.0f / Z;

        float of[8];
        #pragma unroll
        for (int j = 0; j < 8; ++j) of[j] = 0.f;
        #pragma unroll
        for (int off = 0; off < 49; ++off) {
            const int di = off / 7 - 3, dj = off % 7 - 3;
            short8 vv = *(const short8*)(vp + base0 + (di * PADW + dj) * CH);
            const float ev = e[off];
            #pragma unroll
            for (int j = 0; j < 8; ++j) of[j] += ev * bf2f((unsigned short)vv[j]);
        }
        short8 ov;
        #pragma unroll
        for (int j = 0; j < 8; ++j) ov[j] = (short)f2bf(of[j] * rz);
        *(short8*)(lds + prw * 136 + cb) = ov;
    }
    __syncthreads();

    // ---- phase 2: GEMM 16px x 128och x K=256 (att | xT) ----
    const int l16 = tid & 15;
    const int g   = (tid & 63) >> 4;
    const int wv  = tid >> 6;
    const int o0  = wv * 32;

    f32x4 acc[2];
    const f32x4 z = {0.f, 0.f, 0.f, 0.f};
    acc[0] = z; acc[1] = z;

    #pragma unroll
    for (int kk = 0; kk < 8; ++kk) {
        const int kbase = kk * 32 + g * 8;
        short8 av;
        if (kk < 4) av = *(const short8*)(lds + l16 * 136 + kbase);
        else        av = *(const short8*)(xT + (p0 + l16) * CH + (kbase - 128));
        #pragma unroll
        for (int nt = 0; nt < 2; ++nt) {
            short8 bv = *(const short8*)(Wo + (o0 + nt * 16 + l16) * 256 + kbase);
            acc[nt] = __builtin_amdgcn_mfma_f32_16x16x32_bf16(av, bv, acc[nt], 0, 0, 0);
        }
    }

    __syncthreads();   // att reads done before LDS reuse

    {
        const float* s = sb + 10 * 128;
        const float* bb = sb + 11 * 128;
        #pragma unroll
        for (int nt = 0; nt < 2; ++nt) {
            const int o = o0 + nt * 16 + l16;
            const float sf = s[o], bf = bb[o];
            #pragma unroll
            for (int i = 0; i < 4; ++i) {
                const float vl = acc[nt][i] * sf + bf;      // no ReLU
                lds[o * 24 + g * 4 + i] = (short)f2bf(vl);
            }
        }
    }
    __syncthreads();
    {
        const int row = tid >> 1, half = tid & 1;   // 256 units of 8 f32
        f32x4 lo, hi;
        const short* src = lds + row * 24 + half * 8;
        #pragma unroll
        for (int j = 0; j < 4; ++j) {
            lo[j] = bf2f((unsigned short)src[j]);
            hi[j] = bf2f((unsigned short)src[4 + j]);
        }
        float* dst = out + row * HW_PIX + p0 + half * 8;
        *(f32x4*)dst       = lo;
        *(f32x4*)(dst + 4) = hi;
    }
}

extern "C" void kernel_launch(void* const* d_in, const int* in_sizes, int n_in,
                              void* d_out, int out_size, void* d_ws, size_t ws_size,
                              hipStream_t stream)
{
    const float* x = (const float*)d_in[0];
    short* ws = (short*)d_ws;

    CvtArgs ca;
    ca.w[0] = (const float*)d_in[1];   // w_q1
    ca.w[1] = (const float*)d_in[4];   // w_q2
    ca.w[2] = (const float*)d_in[7];   // w_k1
    ca.w[3] = (const float*)d_in[10];  // w_k2
    ca.w[4] = (const float*)d_in[13];  // w_v
    ca.w[5] = (const float*)d_in[16];  // w_o
    ca.sb[0]  = (const float*)d_in[2];  ca.sb[1]  = (const float*)d_in[3];
    ca.sb[2]  = (const float*)d_in[5];  ca.sb[3]  = (const float*)d_in[6];
    ca.sb[4]  = (const float*)d_in[8];  ca.sb[5]  = (const float*)d_in[9];
    ca.sb[6]  = (const float*)d_in[11]; ca.sb[7]  = (const float*)d_in[12];
    ca.sb[8]  = (const float*)d_in[14]; ca.sb[9]  = (const float*)d_in[15];
    ca.sb[10] = (const float*)d_in[17]; ca.sb[11] = (const float*)d_in[18];

    cvt_k<<<dim3(75), dim3(256), 0, stream>>>(ca, ws);
    qkv_k<<<dim3(1024), dim3(256), 0, stream>>>(x, ws);
    fused_k<<<dim3(1024), dim3(256), 0, stream>>>(ws, (float*)d_out);
}

// Round 7
// 72.737 us; speedup vs baseline: 1.1517x; 1.1517x over previous
//
#include <hip/hip_runtime.h>

// ModalitySpecificLocalSelfAttention — MI355X. f32 I/O, bf16 MFMA internals.
// cvt (weights + zero k/v pads) -> qkv (LDS-staged x, conv1+conv2+v) ->
// fused attention (LDS-staged k then v halos) + final conv.

typedef short short8 __attribute__((ext_vector_type(8)));
typedef float f32x4 __attribute__((ext_vector_type(4)));

#define HW_PIX 16384   // H*W
#define CH 128
#define PADW 134       // 128 + 2*3
#define PSLOT (134 * 134 * 128)   // 2,298,368 elems per padded buffer

// ws layout in 16-bit units
#define WQ1_OFF 0
#define WQ2_OFF 16384
#define WK1_OFF 32768
#define WK2_OFF 49152
#define WV_OFF  65536
#define WO_OFF  81920            // 128x256
#define SB_OFF  114688           // 1536 f32 (3072 shorts)
#define TQ_OFF  131072           // q [p][c], 2,097,152
#define KP_OFF  (TQ_OFF + 2097152)
#define VP_OFF  (KP_OFF + PSLOT)
#define XT_OFF  (VP_OFF + PSLOT)         // x bf16 [p][c]

static __device__ __forceinline__ float bf2f(unsigned short u) {
    union { unsigned int i; float f; } c; c.i = ((unsigned int)u) << 16; return c.f;
}
static __device__ __forceinline__ unsigned short f2bf(float f) {
    union { unsigned int i; float f; } c; c.f = f;
    unsigned int x = c.i;
    return (unsigned short)((x + 0x7fffu + ((x >> 16) & 1u)) >> 16);  // RNE
}

// ---- weights/scale-bias conversion + k/v pad zeroing ----
struct CvtArgs { const float* w[6]; const float* sb[12]; };

__global__ __launch_bounds__(256)
void cvt_k(CvtArgs a, short* __restrict__ ws)
{
    const int u = blockIdx.x * 256 + threadIdx.x;   // 75 blocks = 19200 units
    if (u < 14336) {                                 // 114688 weight elems
        const int s0 = u * 8;
        const int seg = (s0 < 81920) ? (s0 >> 14) : 5;
        const int base = (seg < 5) ? (seg << 14) : 81920;
        const float* fp = a.w[seg] + (s0 - base);
        short8 o;
        #pragma unroll
        for (int j = 0; j < 8; ++j) o[j] = (short)f2bf(fp[j]);
        *(short8*)(ws + s0) = o;
    } else if (u < 15872) {                          // 1536 scale/bias floats
        const int idx = u - 14336;
        ((float*)(ws + SB_OFF))[idx] = a.sb[idx >> 7][idx & 127];
    } else if (u < 15872 + 3144) {                   // zero pad pixels of k,v
        const int idx = u - 15872;
        const int buf = idx / 1572;                  // 0 = k, 1 = v
        const int e   = idx % 1572;
        int row, col;
        if (e < 402)      { row = e / PADW;          col = e % PADW; }
        else if (e < 804) { row = 131 + (e - 402) / PADW; col = (e - 402) % PADW; }
        else { const int r = e - 804; row = 3 + r / 6; const int c = r % 6;
               col = (c < 3) ? c : (128 + c); }
        short* p = ws + (buf ? VP_OFF : KP_OFF) + (row * PADW + col) * CH;
        const short8 z = {0, 0, 0, 0, 0, 0, 0, 0};
        #pragma unroll
        for (int j = 0; j < 16; ++j) *(short8*)(p + j * 8) = z;
    }
}

// ---- fused q=conv2(conv1(x)), k=conv2(conv1(x)), v=conv(x); emits xT ----
// 1024 blocks x 256 thr; tile = 16 px; wave owns 16 px x 32 och.
__global__ __launch_bounds__(256)
void qkv_k(const float* __restrict__ x, short* __restrict__ ws)
{
    const float* sb = (const float*)(ws + SB_OFF);
    const int tid = threadIdx.x;
    const int l16 = tid & 15;
    const int g   = (tid & 63) >> 4;
    const int wv  = tid >> 6;
    const int o0  = wv * 32;
    const int p0  = blockIdx.x * 16;
    const int h = p0 >> 7, w0 = p0 & 127;

    __shared__ short xb[16 * 136];
    __shared__ short tileQ[16 * 136];
    __shared__ short tileK[16 * 136];
    __shared__ short tileV[16 * 136];

    // stage x tile: f32 [c][p] coalesced -> bf16 xb[px][c]
    #pragma unroll
    for (int pass = 0; pass < 2; ++pass) {
        const int u = tid + pass * 256;             // 512 units
        const int c = u >> 2, p4 = (u & 3) * 4;
        f32x4 v = *(const f32x4*)(x + c * HW_PIX + p0 + p4);
        #pragma unroll
        for (int j = 0; j < 4; ++j) xb[(p4 + j) * 136 + c] = (short)f2bf(v[j]);
    }
    __syncthreads();

    // xT global (coalesced, 256 short8 units)
    *(short8*)(ws + XT_OFF + (p0 + (tid >> 4)) * CH + (tid & 15) * 8) =
        *(const short8*)(xb + (tid >> 4) * 136 + (tid & 15) * 8);

    // A-frags from xb
    short8 xa[4];
    #pragma unroll
    for (int kk = 0; kk < 4; ++kk)
        xa[kk] = *(const short8*)(xb + l16 * 136 + kk * 32 + g * 8);

    const f32x4 z = {0.f, 0.f, 0.f, 0.f};
    f32x4 acc[2];

    #define GEMM1(WOFF, SIDX, TILE)                                              \
    {                                                                            \
        acc[0] = z; acc[1] = z;                                                  \
        _Pragma("unroll")                                                        \
        for (int kk = 0; kk < 4; ++kk) {                                         \
            _Pragma("unroll")                                                    \
            for (int nt = 0; nt < 2; ++nt) {                                     \
                short8 bv = *(const short8*)(ws + WOFF +                         \
                    (o0 + nt * 16 + l16) * 128 + kk * 32 + g * 8);               \
                acc[nt] = __builtin_amdgcn_mfma_f32_16x16x32_bf16(xa[kk], bv, acc[nt], 0, 0, 0); \
            }                                                                    \
        }                                                                        \
        _Pragma("unroll")                                                        \
        for (int nt = 0; nt < 2; ++nt) {                                         \
            const int o = o0 + nt * 16 + l16;                                    \
            const float sf = sb[(SIDX) * 128 + o], bf = sb[(SIDX + 1) * 128 + o];\
            _Pragma("unroll")                                                    \
            for (int i = 0; i < 4; ++i) {                                        \
                const float vl = fmaxf(acc[nt][i] * sf + bf, 0.f);               \
                TILE[(g * 4 + i) * 136 + o] = (short)f2bf(vl);                   \
            }                                                                    \
        }                                                                        \
    }
    GEMM1(WQ1_OFF, 0, tileQ)
    GEMM1(WK1_OFF, 4, tileK)
    GEMM1(WV_OFF,  8, tileV)
    #undef GEMM1

    __syncthreads();

    // stage 2: q2/k2 over LDS tiles
    short8 lf[4];
    f32x4 accQ[2], accK[2];
    accQ[0] = z; accQ[1] = z; accK[0] = z; accK[1] = z;
    #pragma unroll
    for (int kk = 0; kk < 4; ++kk) lf[kk] = *(const short8*)(tileQ + l16 * 136 + kk * 32 + g * 8);
    #pragma unroll
    for (int kk = 0; kk < 4; ++kk) {
        #pragma unroll
        for (int nt = 0; nt < 2; ++nt) {
            short8 bv = *(const short8*)(ws + WQ2_OFF + (o0 + nt * 16 + l16) * 128 + kk * 32 + g * 8);
            accQ[nt] = __builtin_amdgcn_mfma_f32_16x16x32_bf16(lf[kk], bv, accQ[nt], 0, 0, 0);
        }
    }
    #pragma unroll
    for (int kk = 0; kk < 4; ++kk) lf[kk] = *(const short8*)(tileK + l16 * 136 + kk * 32 + g * 8);
    #pragma unroll
    for (int kk = 0; kk < 4; ++kk) {
        #pragma unroll
        for (int nt = 0; nt < 2; ++nt) {
            short8 bv = *(const short8*)(ws + WK2_OFF + (o0 + nt * 16 + l16) * 128 + kk * 32 + g * 8);
            accK[nt] = __builtin_amdgcn_mfma_f32_16x16x32_bf16(lf[kk], bv, accK[nt], 0, 0, 0);
        }
    }

    __syncthreads();   // all tile reads done before overwrite

    #pragma unroll
    for (int nt = 0; nt < 2; ++nt) {
        const int o = o0 + nt * 16 + l16;
        const float sfq = sb[2 * 128 + o], bfq = sb[3 * 128 + o];
        const float sfk = sb[6 * 128 + o], bfk = sb[7 * 128 + o];
        #pragma unroll
        for (int i = 0; i < 4; ++i) {
            tileQ[(g * 4 + i) * 136 + o] = (short)f2bf(fmaxf(accQ[nt][i] * sfq + bfq, 0.f));
            tileK[(g * 4 + i) * 136 + o] = (short)f2bf(fmaxf(accK[nt][i] * sfk + bfk, 0.f));
        }
    }

    __syncthreads();

    // coalesced stores: q unpadded; k,v into padded layout
    {
        const int row = tid >> 4, c8 = tid & 15;       // 256 units of 8 elems
        const int soff = row * 136 + c8 * 8;
        const int prow_pad = (h + 3) * PADW + (w0 + row + 3);
        *(short8*)(ws + TQ_OFF + (p0 + row) * CH + c8 * 8) = *(const short8*)(tileQ + soff);
        *(short8*)(ws + KP_OFF + prow_pad * CH + c8 * 8)   = *(const short8*)(tileK + soff);
        *(short8*)(ws + VP_OFF + prow_pad * CH + c8 * 8)   = *(const short8*)(tileV + soff);
    }
}

// ---- fused 7x7 attention (LDS-staged halos) + final conv ----
// 1024 blocks x 256 thr; tile = 16 px in one image row; XCD-swizzled.
__global__ __launch_bounds__(256)
void fused_k(const short* __restrict__ ws, float* __restrict__ out)
{
    const short* q  = ws + TQ_OFF;
    const short* kp = ws + KP_OFF;
    const short* vp = ws + VP_OFF;
    const short* xT = ws + XT_OFF;
    const short* Wo = ws + WO_OFF;
    const float* sb = (const float*)(ws + SB_OFF);

    __shared__ short hal[7 * 22 * 128];   // 19712 elems = 39.4 KB (k, then v, then out)
    __shared__ short attT[16 * 136];      // attention out tile

    const int tid = threadIdx.x;
    const int b   = blockIdx.x;
    const int t   = (b & 7) * 128 + (b >> 3);       // XCD-contiguous tiles
    const int p0  = t * 16;
    const int h = p0 >> 7, w0 = p0 & 127;

    const int l16 = tid & 15;
    const int px  = tid >> 4;            // 0..15, column within tile
    const int cb  = l16 * 8;
    const long hbase = ((long)h * PADW + w0) * CH;   // halo origin in padded buf

    // q for this (px, ch-group)
    float qf[8];
    {
        short8 qv = *(const short8*)(q + (p0 + px) * CH + cb);
        #pragma unroll
        for (int j = 0; j < 8; ++j) qf[j] = bf2f((unsigned short)qv[j]);
    }

    // ---- stage K halo: rows h..h+6 (padded), cols w0..w0+21 ----
    #pragma unroll
    for (int u = tid; u < 2464; u += 256) {          // 2464 short8 units
        const int i = u / 352, rem = u - i * 352;
        const int j = rem >> 4, c8 = rem & 15;
        *(short8*)(hal + (i * 22 + j) * 128 + c8 * 8) =
            *(const short8*)(kp + hbase + ((long)i * PADW + j) * CH + c8 * 8);
    }
    __syncthreads();

    // ---- QK from LDS ----
    float e[49];
    #pragma unroll
    for (int off = 0; off < 49; ++off) {
        const int di = off / 7, dj = off % 7;
        short8 kv = *(const short8*)(hal + (di * 22 + px + dj) * 128 + cb);
        float s = 0.f;
        #pragma unroll
        for (int j = 0; j < 8; ++j) s += qf[j] * bf2f((unsigned short)kv[j]);
        s += __shfl_xor(s, 1, 16);
        s += __shfl_xor(s, 2, 16);
        s += __shfl_xor(s, 4, 16);
        s += __shfl_xor(s, 8, 16);
        e[off] = s;
    }

    float m = e[0];
    #pragma unroll
    for (int off = 1; off < 49; ++off) m = fmaxf(m, e[off]);
    float Z = 0.f;
    #pragma unroll
    for (int off = 0; off < 49; ++off) { const float ex = __expf(e[off] - m); e[off] = ex; Z += ex; }
    const float rz = 1.0f / Z;

    __syncthreads();   // everyone done reading K halo

    // ---- stage V halo over the same LDS ----
    #pragma unroll
    for (int u = tid; u < 2464; u += 256) {
        const int i = u / 352, rem = u - i * 352;
        const int j = rem >> 4, c8 = rem & 15;
        *(short8*)(hal + (i * 22 + j) * 128 + c8 * 8) =
            *(const short8*)(vp + hbase + ((long)i * PADW + j) * CH + c8 * 8);
    }
    __syncthreads();

    // ---- PV from LDS ----
    float of[8];
    #pragma unroll
    for (int j = 0; j < 8; ++j) of[j] = 0.f;
    #pragma unroll
    for (int off = 0; off < 49; ++off) {
        const int di = off / 7, dj = off % 7;
        short8 vv = *(const short8*)(hal + (di * 22 + px + dj) * 128 + cb);
        const float ev = e[off];
        #pragma unroll
        for (int j = 0; j < 8; ++j) of[j] += ev * bf2f((unsigned short)vv[j]);
    }
    {
        short8 ov;
        #pragma unroll
        for (int j = 0; j < 8; ++j) ov[j] = (short)f2bf(of[j] * rz);
        *(short8*)(attT + px * 136 + cb) = ov;
    }
    __syncthreads();   // attT complete; hal free for reuse

    // ---- final conv: 16px x 128och x K=256 (attT | xT) ----
    const int g  = (tid & 63) >> 4;
    const int wv = tid >> 6;
    const int o0 = wv * 32;

    f32x4 acc[2];
    const f32x4 z = {0.f, 0.f, 0.f, 0.f};
    acc[0] = z; acc[1] = z;

    #pragma unroll
    for (int kk = 0; kk < 8; ++kk) {
        const int kbase = kk * 32 + g * 8;
        short8 av;
        if (kk < 4) av = *(const short8*)(attT + l16 * 136 + kbase);
        else        av = *(const short8*)(xT + (p0 + l16) * CH + (kbase - 128));
        #pragma unroll
        for (int nt = 0; nt < 2; ++nt) {
            short8 bv = *(const short8*)(Wo + (o0 + nt * 16 + l16) * 256 + kbase);
            acc[nt] = __builtin_amdgcn_mfma_f32_16x16x32_bf16(av, bv, acc[nt], 0, 0, 0);
        }
    }

    // epilogue into hal-region (free), transpose, f32 [c][p] store
    short* outT = hal;                   // [128][24]
    {
        const float* s  = sb + 10 * 128;
        const float* bb = sb + 11 * 128;
        #pragma unroll
        for (int nt = 0; nt < 2; ++nt) {
            const int o = o0 + nt * 16 + l16;
            const float sf = s[o], bf = bb[o];
            #pragma unroll
            for (int i = 0; i < 4; ++i) {
                const float vl = acc[nt][i] * sf + bf;      // no ReLU
                outT[o * 24 + g * 4 + i] = (short)f2bf(vl);
            }
        }
    }
    __syncthreads();
    {
        const int row = tid >> 1, half = tid & 1;   // 256 units of 8 f32
        const short* src = outT + row * 24 + half * 8;
        f32x4 lo, hi;
        #pragma unroll
        for (int j = 0; j < 4; ++j) {
            lo[j] = bf2f((unsigned short)src[j]);
            hi[j] = bf2f((unsigned short)src[4 + j]);
        }
        float* dst = out + row * HW_PIX + p0 + half * 8;
        *(f32x4*)dst       = lo;
        *(f32x4*)(dst + 4) = hi;
    }
}

extern "C" void kernel_launch(void* const* d_in, const int* in_sizes, int n_in,
                              void* d_out, int out_size, void* d_ws, size_t ws_size,
                              hipStream_t stream)
{
    const float* x = (const float*)d_in[0];
    short* ws = (short*)d_ws;

    CvtArgs ca;
    ca.w[0] = (const float*)d_in[1];   // w_q1
    ca.w[1] = (const float*)d_in[4];   // w_q2
    ca.w[2] = (const float*)d_in[7];   // w_k1
    ca.w[3] = (const float*)d_in[10];  // w_k2
    ca.w[4] = (const float*)d_in[13];  // w_v
    ca.w[5] = (const float*)d_in[16];  // w_o
    ca.sb[0]  = (const float*)d_in[2];  ca.sb[1]  = (const float*)d_in[3];
    ca.sb[2]  = (const float*)d_in[5];  ca.sb[3]  = (const float*)d_in[6];
    ca.sb[4]  = (const float*)d_in[8];  ca.sb[5]  = (const float*)d_in[9];
    ca.sb[6]  = (const float*)d_in[11]; ca.sb[7]  = (const float*)d_in[12];
    ca.sb[8]  = (const float*)d_in[14]; ca.sb[9]  = (const float*)d_in[15];
    ca.sb[10] = (const float*)d_in[17]; ca.sb[11] = (const float*)d_in[18];

    cvt_k<<<dim3(75), dim3(256), 0, stream>>>(ca, ws);
    qkv_k<<<dim3(1024), dim3(256), 0, stream>>>(x, ws);
    fused_k<<<dim3(1024), dim3(256), 0, stream>>>(ws, (float*)d_out);
}

// Round 9
// 62.879 us; speedup vs baseline: 1.3323x; 1.1568x over previous
//
#include <hip/hip_runtime.h>

// ModalitySpecificLocalSelfAttention — MI355X. f32 I/O, bf16 MFMA internals.
// 3 dispatches:
//   cvt_k: weights f32->bf16, scale/bias -> f32 ws, zero k/v pad pixels.
//   qkv_k: per 4x4-px tile: q=conv2(conv1(x)), k=conv2(conv1(x)), v=conv(x);
//          q,xT -> [p][c] global; k,v -> padded [134][134][128] global.
//   att_k: stage K halo [10][10][128] -> S=Q*K^T via MFMA (wave 0, no
//          shuffle chain) -> masked softmax (P f32 in LDS) -> stage V halo
//          -> PV (VALU, shuffle-free) -> final conv (att|x) -> f32 [c][p].

typedef short short8 __attribute__((ext_vector_type(8)));
typedef short short4v __attribute__((ext_vector_type(4)));
typedef float f32x4 __attribute__((ext_vector_type(4)));

#define HW_PIX 16384   // H*W
#define CH 128
#define PADW 134       // 128 + 2*3
#define PSLOT (134 * 134 * 128)

// ws layout in 16-bit units
#define WQ1_OFF 0
#define WQ2_OFF 16384
#define WK1_OFF 32768
#define WK2_OFF 49152
#define WV_OFF  65536
#define WO_OFF  81920            // 128x256
#define SB_OFF  114688           // 1536 f32 (3072 shorts)
#define TQ_OFF  117760           // q [p][c]
#define XT_OFF  (TQ_OFF + 2097152)
#define KP_OFF  (XT_OFF + 2097152)
#define VP_OFF  (KP_OFF + PSLOT)

static __device__ __forceinline__ float bf2f(unsigned short u) {
    union { unsigned int i; float f; } c; c.i = ((unsigned int)u) << 16; return c.f;
}
static __device__ __forceinline__ unsigned short f2bf(float f) {
    union { unsigned int i; float f; } c; c.f = f;
    unsigned int x = c.i;
    return (unsigned short)((x + 0x7fffu + ((x >> 16) & 1u)) >> 16);  // RNE
}

// ---- weights/scale-bias conversion + k/v pad zeroing ----
struct CvtArgs { const float* w[6]; const float* sb[12]; };

__global__ __launch_bounds__(256)
void cvt_k(CvtArgs a, short* __restrict__ ws)
{
    const int u = blockIdx.x * 256 + threadIdx.x;   // 75 blocks = 19200 units
    if (u < 14336) {                                 // 114688 weight elems
        const int s0 = u * 8;
        const int seg = (s0 < 81920) ? (s0 >> 14) : 5;
        const int base = (seg < 5) ? (seg << 14) : 81920;
        const float* fp = a.w[seg] + (s0 - base);
        short8 o;
        #pragma unroll
        for (int j = 0; j < 8; ++j) o[j] = (short)f2bf(fp[j]);
        *(short8*)(ws + s0) = o;
    } else if (u < 15872) {                          // 1536 scale/bias floats
        const int idx = u - 14336;
        ((float*)(ws + SB_OFF))[idx] = a.sb[idx >> 7][idx & 127];
    } else if (u < 15872 + 3144) {                   // zero pad pixels of k,v
        const int idx = u - 15872;
        const int buf = idx / 1572;                  // 0 = k, 1 = v
        const int e   = idx % 1572;
        int row, col;
        if (e < 402)      { row = e / PADW;          col = e % PADW; }
        else if (e < 804) { row = 131 + (e - 402) / PADW; col = (e - 402) % PADW; }
        else { const int r = e - 804; row = 3 + r / 6; const int c = r % 6;
               col = (c < 3) ? c : (128 + c); }
        short* p = ws + (buf ? VP_OFF : KP_OFF) + (row * PADW + col) * CH;
        const short8 z = {0, 0, 0, 0, 0, 0, 0, 0};
        #pragma unroll
        for (int j = 0; j < 16; ++j) *(short8*)(p + j * 8) = z;
    }
}

// ---- q/k/v projections over 4x4-px tiles ----
__global__ __launch_bounds__(256)
void qkv_k(const float* __restrict__ x, short* __restrict__ ws)
{
    const float* sb = (const float*)(ws + SB_OFF);
    const int tid = threadIdx.x;
    const int bid = blockIdx.x;
    const int t   = (bid & 7) * 128 + (bid >> 3);   // XCD bands
    const int tr = t >> 5, tc = t & 31;
    const int h0 = tr * 4, w0 = tc * 4;

    const int l16 = tid & 15;
    const int g   = (tid & 63) >> 4;
    const int wv  = tid >> 6;
    const int o0  = wv * 32;

    __shared__ short xb[16 * 136];
    __shared__ short tileQ[16 * 136];
    __shared__ short tileK[16 * 136];
    __shared__ short tileV[16 * 136];

    // stage x tile: f32 [c][p] -> bf16 xb[px][c], px = r*4+cl
    #pragma unroll
    for (int pass = 0; pass < 2; ++pass) {
        const int u = tid + pass * 256;             // 512 units
        const int c = u >> 2, r = u & 3;
        f32x4 v = *(const f32x4*)(x + c * HW_PIX + (h0 + r) * 128 + w0);
        #pragma unroll
        for (int j = 0; j < 4; ++j) xb[(r * 4 + j) * 136 + c] = (short)f2bf(v[j]);
    }
    __syncthreads();

    // xT -> global [p][c]
    {
        const int px = tid >> 4, c8 = tid & 15;
        const int p_img = (h0 + (px >> 2)) * 128 + w0 + (px & 3);
        *(short8*)(ws + XT_OFF + p_img * CH + c8 * 8) =
            *(const short8*)(xb + px * 136 + c8 * 8);
    }

    short8 xa[4];
    #pragma unroll
    for (int kk = 0; kk < 4; ++kk)
        xa[kk] = *(const short8*)(xb + l16 * 136 + kk * 32 + g * 8);

    const f32x4 z = {0.f, 0.f, 0.f, 0.f};
    f32x4 acc[2];

    #define GEMM1(WOFF, SIDX, TILE)                                              \
    {                                                                            \
        acc[0] = z; acc[1] = z;                                                  \
        _Pragma("unroll")                                                        \
        for (int kk = 0; kk < 4; ++kk) {                                         \
            _Pragma("unroll")                                                    \
            for (int nt = 0; nt < 2; ++nt) {                                     \
                short8 bv = *(const short8*)(ws + WOFF +                         \
                    (o0 + nt * 16 + l16) * 128 + kk * 32 + g * 8);               \
                acc[nt] = __builtin_amdgcn_mfma_f32_16x16x32_bf16(xa[kk], bv, acc[nt], 0, 0, 0); \
            }                                                                    \
        }                                                                        \
        _Pragma("unroll")                                                        \
        for (int nt = 0; nt < 2; ++nt) {                                         \
            const int o = o0 + nt * 16 + l16;                                    \
            const float sf = sb[(SIDX) * 128 + o], bf = sb[(SIDX + 1) * 128 + o];\
            _Pragma("unroll")                                                    \
            for (int i = 0; i < 4; ++i) {                                        \
                const float vl = fmaxf(acc[nt][i] * sf + bf, 0.f);               \
                TILE[(g * 4 + i) * 136 + o] = (short)f2bf(vl);                   \
            }                                                                    \
        }                                                                        \
    }
    GEMM1(WQ1_OFF, 0, tileQ)
    GEMM1(WK1_OFF, 4, tileK)
    GEMM1(WV_OFF,  8, tileV)
    #undef GEMM1

    __syncthreads();

    // stage 2: q2 over tileQ, k2 over tileK
    short8 lf[4];
    f32x4 accQ[2], accK[2];
    accQ[0] = z; accQ[1] = z; accK[0] = z; accK[1] = z;
    #pragma unroll
    for (int kk = 0; kk < 4; ++kk) lf[kk] = *(const short8*)(tileQ + l16 * 136 + kk * 32 + g * 8);
    #pragma unroll
    for (int kk = 0; kk < 4; ++kk) {
        #pragma unroll
        for (int nt = 0; nt < 2; ++nt) {
            short8 bv = *(const short8*)(ws + WQ2_OFF + (o0 + nt * 16 + l16) * 128 + kk * 32 + g * 8);
            accQ[nt] = __builtin_amdgcn_mfma_f32_16x16x32_bf16(lf[kk], bv, accQ[nt], 0, 0, 0);
        }
    }
    #pragma unroll
    for (int kk = 0; kk < 4; ++kk) lf[kk] = *(const short8*)(tileK + l16 * 136 + kk * 32 + g * 8);
    #pragma unroll
    for (int kk = 0; kk < 4; ++kk) {
        #pragma unroll
        for (int nt = 0; nt < 2; ++nt) {
            short8 bv = *(const short8*)(ws + WK2_OFF + (o0 + nt * 16 + l16) * 128 + kk * 32 + g * 8);
            accK[nt] = __builtin_amdgcn_mfma_f32_16x16x32_bf16(lf[kk], bv, accK[nt], 0, 0, 0);
        }
    }
    __syncthreads();   // q1/k1 reads done before overwrite

    #pragma unroll
    for (int nt = 0; nt < 2; ++nt) {
        const int o = o0 + nt * 16 + l16;
        const float sfq = sb[2 * 128 + o], bfq = sb[3 * 128 + o];
        const float sfk = sb[6 * 128 + o], bfk = sb[7 * 128 + o];
        #pragma unroll
        for (int i = 0; i < 4; ++i) {
            tileQ[(g * 4 + i) * 136 + o] = (short)f2bf(fmaxf(accQ[nt][i] * sfq + bfq, 0.f));
            tileK[(g * 4 + i) * 136 + o] = (short)f2bf(fmaxf(accK[nt][i] * sfk + bfk, 0.f));
        }
    }
    __syncthreads();

    // stores: q -> TQ [p][c]; k,v -> padded global
    {
        const int px = tid >> 4, c8 = tid & 15;
        const int soff = px * 136 + c8 * 8;
        const int p_img = (h0 + (px >> 2)) * 128 + w0 + (px & 3);
        const int pr = h0 + (px >> 2) + 3, pc = w0 + (px & 3) + 3;
        const int doff = (pr * PADW + pc) * CH + c8 * 8;
        *(short8*)(ws + TQ_OFF + p_img * CH + c8 * 8) = *(const short8*)(tileQ + soff);
        *(short8*)(ws + KP_OFF + doff) = *(const short8*)(tileK + soff);
        *(short8*)(ws + VP_OFF + doff) = *(const short8*)(tileV + soff);
    }
}

// ---- attention (MFMA QK) + final conv over 4x4-px tiles ----
__global__ __launch_bounds__(256)
void att_k(const short* __restrict__ ws, float* __restrict__ out)
{
    const float* sb = (const float*)(ws + SB_OFF);

    __shared__ __align__(16) short hal[112 * 128];   // K halo, then V halo, then outT
    __shared__ __align__(16) short qTl[16 * 136];
    __shared__ __align__(16) short xbl[16 * 136];
    __shared__ __align__(16) short attT[16 * 136];
    __shared__ float Pf[16 * 116];
    __shared__ float rzL[16];

    const int tid = threadIdx.x;
    const int bid = blockIdx.x;
    const int t   = (bid & 7) * 128 + (bid >> 3);
    const int tr = t >> 5, tc = t & 31;
    const int h0 = tr * 4, w0 = tc * 4;

    const int l16 = tid & 15;
    const int g   = (tid & 63) >> 4;
    const int wv  = tid >> 6;

    // ---- stage K halo [10][10][128] + q tile ----
    for (int u = tid; u < 1600 + 256; u += 256) {
        if (u < 1600) {
            const int di = u / 160, rem = u - di * 160;
            const int j = rem >> 4, c8 = rem & 15;
            *(short8*)(hal + (di * 10 + j) * 128 + c8 * 8) =
                *(const short8*)(ws + KP_OFF + ((h0 + di) * PADW + (w0 + j)) * CH + c8 * 8);
        } else {
            const int v = u - 1600;
            const int px = v >> 4, c8 = v & 15;
            const int p_img = (h0 + (px >> 2)) * 128 + w0 + (px & 3);
            *(short8*)(qTl + px * 136 + c8 * 8) =
                *(const short8*)(ws + TQ_OFF + p_img * CH + c8 * 8);
        }
    }
    __syncthreads();

    // ---- wave 0: S = Q * K_halo^T via MFMA; masked softmax; P,rz -> LDS ----
    if (wv == 0) {
        short8 af[4];
        #pragma unroll
        for (int kk = 0; kk < 4; ++kk)
            af[kk] = *(const short8*)(qTl + l16 * 136 + kk * 32 + g * 8);

        f32x4 S[7];
        const f32x4 z = {0.f, 0.f, 0.f, 0.f};
        #pragma unroll
        for (int nt = 0; nt < 7; ++nt) S[nt] = z;
        #pragma unroll
        for (int kk = 0; kk < 4; ++kk) {
            #pragma unroll
            for (int nt = 0; nt < 7; ++nt) {
                short8 bv = *(const short8*)(hal + (nt * 16 + l16) * 128 + kk * 32 + g * 8);
                S[nt] = __builtin_amdgcn_mfma_f32_16x16x32_bf16(af[kk], bv, S[nt], 0, 0, 0);
            }
        }
        // per row i: mask -> max -> exp -> sum (reduce across 16 col-lanes)
        #pragma unroll
        for (int i = 0; i < 4; ++i) {
            const int px = g * 4 + i;
            const int r = px >> 2, cl = px & 3;
            float vals[7];
            float mx = -3.0e38f;
            #pragma unroll
            for (int nt = 0; nt < 7; ++nt) {
                const int col = nt * 16 + l16;
                const int hr = col / 10, hc = col - hr * 10;
                const bool ok = (col < 100) &&
                                ((unsigned)(hr - r) < 7u) && ((unsigned)(hc - cl) < 7u);
                vals[nt] = ok ? S[nt][i] : -3.0e38f;
                mx = fmaxf(mx, vals[nt]);
            }
            mx = fmaxf(mx, __shfl_xor(mx, 1, 16));
            mx = fmaxf(mx, __shfl_xor(mx, 2, 16));
            mx = fmaxf(mx, __shfl_xor(mx, 4, 16));
            mx = fmaxf(mx, __shfl_xor(mx, 8, 16));
            float zs = 0.f;
            #pragma unroll
            for (int nt = 0; nt < 7; ++nt) {
                const float ev = (vals[nt] > -1.0e37f) ? __expf(vals[nt] - mx) : 0.f;
                zs += ev;
                Pf[px * 116 + nt * 16 + l16] = ev;
            }
            zs += __shfl_xor(zs, 1, 16);
            zs += __shfl_xor(zs, 2, 16);
            zs += __shfl_xor(zs, 4, 16);
            zs += __shfl_xor(zs, 8, 16);
            if (l16 == 0) rzL[px] = 1.0f / zs;
        }
    }
    __syncthreads();

    // ---- stage V halo over hal + x tile ----
    for (int u = tid; u < 1600 + 256; u += 256) {
        if (u < 1600) {
            const int di = u / 160, rem = u - di * 160;
            const int j = rem >> 4, c8 = rem & 15;
            *(short8*)(hal + (di * 10 + j) * 128 + c8 * 8) =
                *(const short8*)(ws + VP_OFF + ((h0 + di) * PADW + (w0 + j)) * CH + c8 * 8);
        } else {
            const int v = u - 1600;
            const int px = v >> 4, c8 = v & 15;
            const int p_img = (h0 + (px >> 2)) * 128 + w0 + (px & 3);
            *(short8*)(xbl + px * 136 + c8 * 8) =
                *(const short8*)(ws + XT_OFF + p_img * CH + c8 * 8);
        }
    }
    __syncthreads();

    // ---- PV (shuffle-free VALU) ----
    {
        const int px = tid >> 4;
        const int r = px >> 2, cl = px & 3;
        const int cb = l16 * 8;
        float of[8];
        #pragma unroll
        for (int j = 0; j < 8; ++j) of[j] = 0.f;
        #pragma unroll
        for (int off = 0; off < 49; ++off) {
            const int di = off / 7, dj = off % 7;
            const int hp = (r + di) * 10 + cl + dj;
            const float ev = Pf[px * 116 + hp];
            short8 vv = *(const short8*)(hal + hp * 128 + cb);
            #pragma unroll
            for (int j = 0; j < 8; ++j) of[j] += ev * bf2f((unsigned short)vv[j]);
        }
        const float rz = rzL[px];
        short8 ov;
        #pragma unroll
        for (int j = 0; j < 8; ++j) ov[j] = (short)f2bf(of[j] * rz);
        *(short8*)(attT + px * 136 + cb) = ov;
    }
    __syncthreads();   // attT ready; hal reads done

    // ---- final conv: 16px x 128och x K=256 (attT | xbl) ----
    const int o0 = wv * 32;
    f32x4 fac[2];
    const f32x4 zz = {0.f, 0.f, 0.f, 0.f};
    fac[0] = zz; fac[1] = zz;
    #pragma unroll
    for (int kk = 0; kk < 8; ++kk) {
        const int kbase = kk * 32 + g * 8;
        short8 av;
        if (kk < 4) av = *(const short8*)(attT + l16 * 136 + kbase);
        else        av = *(const short8*)(xbl + l16 * 136 + (kbase - 128));
        #pragma unroll
        for (int nt = 0; nt < 2; ++nt) {
            short8 bv = *(const short8*)(ws + WO_OFF + (o0 + nt * 16 + l16) * 256 + kbase);
            fac[nt] = __builtin_amdgcn_mfma_f32_16x16x32_bf16(av, bv, fac[nt], 0, 0, 0);
        }
    }

    short* outT = hal;                    // [128][24]
    {
        const float* s  = sb + 10 * 128;
        const float* bb = sb + 11 * 128;
        #pragma unroll
        for (int nt = 0; nt < 2; ++nt) {
            const int o = o0 + nt * 16 + l16;
            const float sf = s[o], bf = bb[o];
            #pragma unroll
            for (int i = 0; i < 4; ++i) {
                const float vl = fac[nt][i] * sf + bf;      // no ReLU
                outT[o * 24 + g * 4 + i] = (short)f2bf(vl);
            }
        }
    }
    __syncthreads();
    #pragma unroll
    for (int pass = 0; pass < 2; ++pass) {
        const int u = tid + pass * 256;              // 512 units of 4 f32
        const int c = u >> 2, rr = u & 3;
        short4v sv = *(const short4v*)(outT + c * 24 + rr * 4);
        f32x4 fv;
        #pragma unroll
        for (int j = 0; j < 4; ++j) fv[j] = bf2f((unsigned short)sv[j]);
        *(f32x4*)(out + c * HW_PIX + (h0 + rr) * 128 + w0) = fv;
    }
}

extern "C" void kernel_launch(void* const* d_in, const int* in_sizes, int n_in,
                              void* d_out, int out_size, void* d_ws, size_t ws_size,
                              hipStream_t stream)
{
    const float* x = (const float*)d_in[0];
    short* ws = (short*)d_ws;

    CvtArgs ca;
    ca.w[0] = (const float*)d_in[1];   // w_q1
    ca.w[1] = (const float*)d_in[4];   // w_q2
    ca.w[2] = (const float*)d_in[7];   // w_k1
    ca.w[3] = (const float*)d_in[10];  // w_k2
    ca.w[4] = (const float*)d_in[13];  // w_v
    ca.w[5] = (const float*)d_in[16];  // w_o
    ca.sb[0]  = (const float*)d_in[2];  ca.sb[1]  = (const float*)d_in[3];
    ca.sb[2]  = (const float*)d_in[5];  ca.sb[3]  = (const float*)d_in[6];
    ca.sb[4]  = (const float*)d_in[8];  ca.sb[5]  = (const float*)d_in[9];
    ca.sb[6]  = (const float*)d_in[11]; ca.sb[7]  = (const float*)d_in[12];
    ca.sb[8]  = (const float*)d_in[14]; ca.sb[9]  = (const float*)d_in[15];
    ca.sb[10] = (const float*)d_in[17]; ca.sb[11] = (const float*)d_in[18];

    cvt_k<<<dim3(75), dim3(256), 0, stream>>>(ca, ws);
    qkv_k<<<dim3(1024), dim3(256), 0, stream>>>(x, ws);
    att_k<<<dim3(1024), dim3(256), 0, stream>>>(ws, (float*)d_out);
}